// Round 2
// baseline (96.596 us; speedup 1.0000x reference)
//
#include <hip/hip_runtime.h>

#define NBATCH 256
#define LAMBDA_COORD 5.0f
#define LAMBDA_NOOBJ 0.5f

// Each thread processes one 60-float segment = exactly 2 cells (30 ch each).
// 60 floats = 15 float4, 240B-aligned. All channel indices are compile-time
// constants after unroll; objectness comes from the already-loaded t[4]/t[34].
__global__ __launch_bounds__(256) void yolo_loss_seg_kernel(
    const float* __restrict__ pred,
    const float* __restrict__ targ,
    float* __restrict__ out,
    int nseg)
{
    float acc = 0.0f;
    int seg = blockIdx.x * blockDim.x + threadIdx.x;

    if (seg < nseg) {
        const float4* __restrict__ p4 =
            reinterpret_cast<const float4*>(pred + (size_t)seg * 60);
        const float4* __restrict__ t4 =
            reinterpret_cast<const float4*>(targ + (size_t)seg * 60);

        float p[60], t[60];
        #pragma unroll
        for (int k = 0; k < 15; ++k) {
            float4 v = p4[k];
            p[4*k+0] = v.x; p[4*k+1] = v.y; p[4*k+2] = v.z; p[4*k+3] = v.w;
        }
        #pragma unroll
        for (int k = 0; k < 15; ++k) {
            float4 v = t4[k];
            t[4*k+0] = v.x; t[4*k+1] = v.y; t[4*k+2] = v.z; t[4*k+3] = v.w;
        }

        #pragma unroll
        for (int cell = 0; cell < 2; ++cell) {
            const int b = cell * 30;
            float dx = p[b+0] - t[b+0];
            float dy = p[b+1] - t[b+1];
            float dw = sqrtf(p[b+2]) - sqrtf(t[b+2]);
            float dh = sqrtf(p[b+3]) - sqrtf(t[b+3]);
            float dconf = p[b+4] - t[b+4];
            float cls = 0.0f;
            #pragma unroll
            for (int c = 5; c < 30; ++c) {
                float d = p[b+c] - t[b+c];
                cls += d * d;
            }
            float conf2 = dconf * dconf;
            float A = LAMBDA_COORD * (dx*dx + dy*dy + dw*dw + dh*dh) + conf2 + cls;
            float obj = (t[b+4] == 1.0f) ? 1.0f : 0.0f;
            acc += obj * A + LAMBDA_NOOBJ * (1.0f - obj) * conf2;
        }
    }

    // wave64 shuffle reduction
    #pragma unroll
    for (int off = 32; off > 0; off >>= 1)
        acc += __shfl_down(acc, off, 64);

    __shared__ float lds[4];
    int lane = threadIdx.x & 63;
    int wid  = threadIdx.x >> 6;
    if (lane == 0) lds[wid] = acc;
    __syncthreads();
    if (threadIdx.x == 0) {
        float s = lds[0] + lds[1] + lds[2] + lds[3];
        atomicAdd(out, s * (1.0f / (float)NBATCH));
    }
}

extern "C" void kernel_launch(void* const* d_in, const int* in_sizes, int n_in,
                              void* d_out, int out_size, void* d_ws, size_t ws_size,
                              hipStream_t stream)
{
    const float* pred = (const float*)d_in[0];
    const float* targ = (const float*)d_in[1];
    float* out = (float*)d_out;

    // zero the accumulator (harness poisons once, never re-poisons between replays)
    hipMemsetAsync(out, 0, sizeof(float), stream);

    int n    = in_sizes[0];        // 256*56*56*30 = 24,084,480
    int nseg = n / 60;             // 401,408 two-cell segments
    int blocks = (nseg + 255) / 256;  // 1568

    yolo_loss_seg_kernel<<<blocks, 256, 0, stream>>>(pred, targ, out, nseg);
}

// Round 3
// 59.816 us; speedup vs baseline: 1.6149x; 1.6149x over previous
//
#include <hip/hip_runtime.h>

#define NBATCH 256
#define NCH 30

// Flat coalesced float4 mapping (lane i -> float4 i), grid sized so the
// grid-stride in floats is a multiple of 30: each thread's channel pattern
// (c0..c0+3), sqrt flags, and weight coefficients are loop-invariant.
// w(c, obj) = obj*A + B:  c<4 -> (5,0);  c==4 -> (0.5,0.5);  c>=5 -> (1,0).
__global__ __launch_bounds__(256) void yolo_loss_aligned_kernel(
    const float* __restrict__ pred,
    const float* __restrict__ targ,
    float* __restrict__ out,
    int n4)
{
    const int nthreads = gridDim.x * blockDim.x;   // 1920*256; *4 % 30 == 0
    const int tid = blockIdx.x * blockDim.x + threadIdx.x;

    const int e0 = tid * 4;                 // first flat element index
    const int c0 = e0 % NCH;                // channel of element 0 (invariant)
    int cidx = (e0 / NCH) * NCH + 4;        // flat index of this cell's conf
    const int dconf = nthreads * 4;         // conf index advance per iter
    const int hioff = (c0 + 3 >= NCH) ? NCH : 0;  // straddle -> next cell's conf

    float A[4], B[4];
    bool  SQ[4], LO[4];
    #pragma unroll
    for (int k = 0; k < 4; ++k) {
        int c = c0 + k; if (c >= NCH) c -= NCH;
        SQ[k] = (c == 2 || c == 3);
        LO[k] = (c0 + k) < NCH;
        if (c < 4)       { A[k] = 5.0f; B[k] = 0.0f; }
        else if (c == 4) { A[k] = 0.5f; B[k] = 0.5f; }
        else             { A[k] = 1.0f; B[k] = 0.0f; }
    }

    const float4* __restrict__ p4 = reinterpret_cast<const float4*>(pred);
    const float4* __restrict__ t4 = reinterpret_cast<const float4*>(targ);

    float acc = 0.0f;
    for (int i = tid; i < n4; i += nthreads, cidx += dconf) {
        float4 pv = p4[i];
        float4 tv = t4[i];
        float conf_lo = targ[cidx];
        float conf_hi = targ[cidx + hioff];      // == conf_lo when no straddle
        float obj_lo = (conf_lo == 1.0f) ? 1.0f : 0.0f;
        float obj_hi = (conf_hi == 1.0f) ? 1.0f : 0.0f;

        float pe[4] = {pv.x, pv.y, pv.z, pv.w};
        float te[4] = {tv.x, tv.y, tv.z, tv.w};
        #pragma unroll
        for (int k = 0; k < 4; ++k) {
            float p = pe[k], t = te[k];
            float d   = SQ[k] ? (sqrtf(p) - sqrtf(t)) : (p - t);
            float obj = LO[k] ? obj_lo : obj_hi;
            float w   = fmaf(obj, A[k], B[k]);
            acc = fmaf(w, d * d, acc);
        }
    }

    // wave64 shuffle reduction
    #pragma unroll
    for (int off = 32; off > 0; off >>= 1)
        acc += __shfl_down(acc, off, 64);

    __shared__ float lds[4];
    int lane = threadIdx.x & 63;
    int wid  = threadIdx.x >> 6;
    if (lane == 0) lds[wid] = acc;
    __syncthreads();
    if (threadIdx.x == 0) {
        float s = lds[0] + lds[1] + lds[2] + lds[3];
        atomicAdd(out, s * (1.0f / (float)NBATCH));
    }
}

extern "C" void kernel_launch(void* const* d_in, const int* in_sizes, int n_in,
                              void* d_out, int out_size, void* d_ws, size_t ws_size,
                              hipStream_t stream)
{
    const float* pred = (const float*)d_in[0];
    const float* targ = (const float*)d_in[1];
    float* out = (float*)d_out;

    hipMemsetAsync(out, 0, sizeof(float), stream);

    int n  = in_sizes[0];   // 24,084,480
    int n4 = n / 4;         // 6,021,120

    // blocks must be a multiple of 15 so nthreads*4 % 30 == 0
    int blocks = 1920;
    yolo_loss_aligned_kernel<<<blocks, 256, 0, stream>>>(pred, targ, out, n4);
}

// Round 4
// 43.161 us; speedup vs baseline: 2.2380x; 1.3859x over previous
//
#include <hip/hip_runtime.h>

#define NBATCH 256
#define NCH 30
#define UF 4

__device__ __forceinline__ float fast_sqrt(float x) {
    float r;
    asm("v_sqrt_f32 %0, %1" : "=v"(r) : "v"(x));
    return r;
}

// Flat coalesced float4 mapping; grid chosen so nthreads*4 % 30 == 0 ->
// per-thread channel phase is loop-invariant. UF=4 superiteration batches
// all global loads before any consume (8x dwordx4 + 8 conf dwords in flight).
// w(c, obj) = obj*A + B:  c<4 -> (5,0);  c==4 -> (0.5,0.5);  c>=5 -> (1,0).
__global__ __launch_bounds__(256, 4) void yolo_loss_uf_kernel(
    const float* __restrict__ pred,
    const float* __restrict__ targ,
    float* __restrict__ out,
    int n4)
{
    const int nthreads = gridDim.x * blockDim.x;   // 1470*256 = 376,320
    const int tid = blockIdx.x * blockDim.x + threadIdx.x;

    const int e0    = tid * 4;              // first flat element index
    const int c0    = e0 % NCH;             // channel phase (loop-invariant)
    const int cell0 = e0 / NCH;
    const int hioff = (c0 + 3 >= NCH) ? NCH : 0;  // straddle -> next cell conf
    const int dconf = nthreads * 4;         // conf flat-index advance per iter

    float A[4], B[4];
    bool  SQ[4], LO[4];
    #pragma unroll
    for (int k = 0; k < 4; ++k) {
        int c = c0 + k; if (c >= NCH) c -= NCH;
        SQ[k] = (c == 2 || c == 3);
        LO[k] = (c0 + k) < NCH;
        if (c < 4)       { A[k] = 5.0f; B[k] = 0.0f; }
        else if (c == 4) { A[k] = 0.5f; B[k] = 0.5f; }
        else             { A[k] = 1.0f; B[k] = 0.0f; }
    }

    const float4* __restrict__ p4 = reinterpret_cast<const float4*>(pred);
    const float4* __restrict__ t4 = reinterpret_cast<const float4*>(targ);
    const float*  __restrict__ cb = targ + (size_t)cell0 * NCH + 4;

    float acc = 0.0f;
    int i = tid;
    size_t coff = 0;

    const int nmain = n4 / (nthreads * UF);   // 4 for the shipped shape
    for (int su = 0; su < nmain; ++su) {
        float4 pv[UF], tv[UF];
        float  clo[UF], chi[UF];
        #pragma unroll
        for (int u = 0; u < UF; ++u) pv[u] = p4[i + u * nthreads];
        #pragma unroll
        for (int u = 0; u < UF; ++u) tv[u] = t4[i + u * nthreads];
        #pragma unroll
        for (int u = 0; u < UF; ++u) {
            clo[u] = cb[coff + (size_t)u * dconf];
            chi[u] = cb[coff + (size_t)u * dconf + hioff];
        }

        #pragma unroll
        for (int u = 0; u < UF; ++u) {
            float obj_lo = (clo[u] == 1.0f) ? 1.0f : 0.0f;
            float obj_hi = (chi[u] == 1.0f) ? 1.0f : 0.0f;
            float pe[4] = {pv[u].x, pv[u].y, pv[u].z, pv[u].w};
            float te[4] = {tv[u].x, tv[u].y, tv[u].z, tv[u].w};
            #pragma unroll
            for (int k = 0; k < 4; ++k) {
                float p = pe[k], t = te[k];
                float dp = p - t;
                float ds = fast_sqrt(p) - fast_sqrt(t);
                float d   = SQ[k] ? ds : dp;
                float obj = LO[k] ? obj_lo : obj_hi;
                float w   = fmaf(obj, A[k], B[k]);
                acc = fmaf(w * d, d, acc);
            }
        }
        i    += UF * nthreads;
        coff += (size_t)UF * dconf;
    }

    // generic tail (empty for the shipped shape; keeps kernel correct for any n4)
    for (; i < n4; i += nthreads, coff += dconf) {
        float4 pv = p4[i];
        float4 tv = t4[i];
        float obj_lo = (cb[coff] == 1.0f) ? 1.0f : 0.0f;
        float obj_hi = (cb[coff + hioff] == 1.0f) ? 1.0f : 0.0f;
        float pe[4] = {pv.x, pv.y, pv.z, pv.w};
        float te[4] = {tv.x, tv.y, tv.z, tv.w};
        #pragma unroll
        for (int k = 0; k < 4; ++k) {
            float p = pe[k], t = te[k];
            float dp = p - t;
            float ds = fast_sqrt(p) - fast_sqrt(t);
            float d   = SQ[k] ? ds : dp;
            float obj = LO[k] ? obj_lo : obj_hi;
            float w   = fmaf(obj, A[k], B[k]);
            acc = fmaf(w * d, d, acc);
        }
    }

    // wave64 shuffle reduction
    #pragma unroll
    for (int off = 32; off > 0; off >>= 1)
        acc += __shfl_down(acc, off, 64);

    __shared__ float lds[4];
    int lane = threadIdx.x & 63;
    int wid  = threadIdx.x >> 6;
    if (lane == 0) lds[wid] = acc;
    __syncthreads();
    if (threadIdx.x == 0) {
        float s = lds[0] + lds[1] + lds[2] + lds[3];
        atomicAdd(out, s * (1.0f / (float)NBATCH));
    }
}

extern "C" void kernel_launch(void* const* d_in, const int* in_sizes, int n_in,
                              void* d_out, int out_size, void* d_ws, size_t ws_size,
                              hipStream_t stream)
{
    const float* pred = (const float*)d_in[0];
    const float* targ = (const float*)d_in[1];
    float* out = (float*)d_out;

    hipMemsetAsync(out, 0, sizeof(float), stream);

    int n  = in_sizes[0];   // 24,084,480
    int n4 = n / 4;         // 6,021,120

    // blocks ≡ 0 (mod 15) keeps the channel phase loop-invariant;
    // 1470 -> 16 iters/thread = exactly 4 UF=4 superiters, no tail.
    int blocks = 1470;
    yolo_loss_uf_kernel<<<blocks, 256, 0, stream>>>(pred, targ, out, n4);
}

// Round 5
// 39.705 us; speedup vs baseline: 2.4328x; 1.0870x over previous
//
#include <hip/hip_runtime.h>

#define NBATCH 256
#define NCH 30
#define UF 4

__device__ __forceinline__ float fast_sqrt(float x) {
    float r;
    asm("v_sqrt_f32 %0, %1" : "=v"(r) : "v"(x));
    return r;
}

// Flat coalesced float4 mapping; grid chosen so nthreads*4 % 30 == 0 ->
// per-thread channel phase is loop-invariant. Each thread does ONE UF=4
// batch (8 dwordx4 + 8 conf dwords in flight, single drain); latency is
// hidden by block turnover (23 blocks/CU queued).
// w(c, obj) = obj*A + B:  c<4 -> (5,0);  c==4 -> (0.5,0.5);  c>=5 -> (1,0).
template <bool USE_WS>
__global__ __launch_bounds__(256, 4) void yolo_loss_main_kernel(
    const float* __restrict__ pred,
    const float* __restrict__ targ,
    float* __restrict__ out,        // USE_WS ? per-block partials : atomic target
    int n4)
{
    const int nthreads = gridDim.x * blockDim.x;
    const int tid = blockIdx.x * blockDim.x + threadIdx.x;

    const int e0    = tid * 4;              // first flat element index
    const int c0    = e0 % NCH;             // channel phase (loop-invariant)
    const int cell0 = e0 / NCH;
    const int hioff = (c0 + 3 >= NCH) ? NCH : 0;  // straddle -> next cell conf
    const int dconf = nthreads * 4;         // conf flat-index advance per iter

    float A[4], B[4];
    bool  SQ[4], LO[4];
    #pragma unroll
    for (int k = 0; k < 4; ++k) {
        int c = c0 + k; if (c >= NCH) c -= NCH;
        SQ[k] = (c == 2 || c == 3);
        LO[k] = (c0 + k) < NCH;
        if (c < 4)       { A[k] = 5.0f; B[k] = 0.0f; }
        else if (c == 4) { A[k] = 0.5f; B[k] = 0.5f; }
        else             { A[k] = 1.0f; B[k] = 0.0f; }
    }

    const float4* __restrict__ p4 = reinterpret_cast<const float4*>(pred);
    const float4* __restrict__ t4 = reinterpret_cast<const float4*>(targ);
    const float*  __restrict__ cb = targ + (size_t)cell0 * NCH + 4;

    float acc = 0.0f;
    int i = tid;
    size_t coff = 0;

    const int nmain = n4 / (nthreads * UF);   // 1 for the shipped shape
    for (int su = 0; su < nmain; ++su) {
        float4 pv[UF], tv[UF];
        float  clo[UF], chi[UF];
        #pragma unroll
        for (int u = 0; u < UF; ++u) pv[u] = p4[i + u * nthreads];
        #pragma unroll
        for (int u = 0; u < UF; ++u) tv[u] = t4[i + u * nthreads];
        #pragma unroll
        for (int u = 0; u < UF; ++u) {
            clo[u] = cb[coff + (size_t)u * dconf];
            chi[u] = cb[coff + (size_t)u * dconf + hioff];
        }

        #pragma unroll
        for (int u = 0; u < UF; ++u) {
            float obj_lo = (clo[u] == 1.0f) ? 1.0f : 0.0f;
            float obj_hi = (chi[u] == 1.0f) ? 1.0f : 0.0f;
            float pe[4] = {pv[u].x, pv[u].y, pv[u].z, pv[u].w};
            float te[4] = {tv[u].x, tv[u].y, tv[u].z, tv[u].w};
            #pragma unroll
            for (int k = 0; k < 4; ++k) {
                float p = pe[k], t = te[k];
                float dp = p - t;
                float ds = fast_sqrt(p) - fast_sqrt(t);
                float d   = SQ[k] ? ds : dp;
                float obj = LO[k] ? obj_lo : obj_hi;
                float w   = fmaf(obj, A[k], B[k]);
                acc = fmaf(w * d, d, acc);
            }
        }
        i    += UF * nthreads;
        coff += (size_t)UF * dconf;
    }

    // generic tail (empty for the shipped shape)
    for (; i < n4; i += nthreads, coff += dconf) {
        float4 pv = p4[i];
        float4 tv = t4[i];
        float obj_lo = (cb[coff] == 1.0f) ? 1.0f : 0.0f;
        float obj_hi = (cb[coff + hioff] == 1.0f) ? 1.0f : 0.0f;
        float pe[4] = {pv.x, pv.y, pv.z, pv.w};
        float te[4] = {tv.x, tv.y, tv.z, tv.w};
        #pragma unroll
        for (int k = 0; k < 4; ++k) {
            float p = pe[k], t = te[k];
            float dp = p - t;
            float ds = fast_sqrt(p) - fast_sqrt(t);
            float d   = SQ[k] ? ds : dp;
            float obj = LO[k] ? obj_lo : obj_hi;
            float w   = fmaf(obj, A[k], B[k]);
            acc = fmaf(w * d, d, acc);
        }
    }

    // wave64 shuffle reduction
    #pragma unroll
    for (int off = 32; off > 0; off >>= 1)
        acc += __shfl_down(acc, off, 64);

    __shared__ float lds[4];
    int lane = threadIdx.x & 63;
    int wid  = threadIdx.x >> 6;
    if (lane == 0) lds[wid] = acc;
    __syncthreads();
    if (threadIdx.x == 0) {
        float s = lds[0] + lds[1] + lds[2] + lds[3];
        if (USE_WS) out[blockIdx.x] = s;
        else        atomicAdd(out, s * (1.0f / (float)NBATCH));
    }
}

// Sum nblocks partials -> out[0], fold the 1/NBATCH.
__global__ __launch_bounds__(256) void yolo_loss_finish_kernel(
    const float* __restrict__ partial, float* __restrict__ out, int n)
{
    float acc = 0.0f;
    for (int i = threadIdx.x; i < n; i += 256) acc += partial[i];
    #pragma unroll
    for (int off = 32; off > 0; off >>= 1)
        acc += __shfl_down(acc, off, 64);
    __shared__ float lds[4];
    int lane = threadIdx.x & 63, wid = threadIdx.x >> 6;
    if (lane == 0) lds[wid] = acc;
    __syncthreads();
    if (threadIdx.x == 0)
        out[0] = (lds[0] + lds[1] + lds[2] + lds[3]) * (1.0f / (float)NBATCH);
}

extern "C" void kernel_launch(void* const* d_in, const int* in_sizes, int n_in,
                              void* d_out, int out_size, void* d_ws, size_t ws_size,
                              hipStream_t stream)
{
    const float* pred = (const float*)d_in[0];
    const float* targ = (const float*)d_in[1];
    float* out = (float*)d_out;

    int n  = in_sizes[0];   // 24,084,480
    int n4 = n / 4;         // 6,021,120

    // blocks ≡ 0 (mod 15) keeps the channel phase loop-invariant;
    // 5880 -> 4 float4/thread = exactly one UF=4 batch, no loop, no tail.
    int blocks = 5880;

    if (ws_size >= (size_t)blocks * sizeof(float)) {
        float* partial = (float*)d_ws;
        yolo_loss_main_kernel<true><<<blocks, 256, 0, stream>>>(pred, targ, partial, n4);
        yolo_loss_finish_kernel<<<1, 256, 0, stream>>>(partial, out, blocks);
    } else {
        hipMemsetAsync(out, 0, sizeof(float), stream);
        yolo_loss_main_kernel<false><<<blocks, 256, 0, stream>>>(pred, targ, out, n4);
    }
}